// Round 2
// baseline (9824.686 us; speedup 1.0000x reference)
//
#include <hip/hip_runtime.h>
#include <hip/hip_bf16.h>

#define N_NODES 100000
#define N_EDGES 1600000
#define N_GRAPHS 512

typedef __hip_bfloat16 bf16;

__device__ __forceinline__ float b2f(bf16 v) { return __bfloat162float(v); }
__device__ __forceinline__ bf16 f2b(float v) { return __float2bfloat16(v); }

// flag-branched input load: isf32 ? fp32 : bf16
__device__ __forceinline__ float ldf(const void* p, long i, int isf32) {
    return isf32 ? ((const float*)p)[i] : b2f(((const bf16*)p)[i]);
}
// flag-branched index load: is64 ? low word of int64 : int32
__device__ __forceinline__ int geti(const int* p, long i, int is64) {
    return is64 ? p[2 * i] : p[i];
}

// ---------------- dtype detection ----------------
__global__ void k_detect(const void* __restrict__ x, const int* __restrict__ ei,
                         int* __restrict__ flags) {
    if (threadIdx.x != 0 || blockIdx.x != 0) return;
    const unsigned short* xu = (const unsigned short*)x;
    int plaus = 0;
    for (int i = 0; i < 256; i++) {
        unsigned short u = xu[2 * i];          // even-indexed 16-bit words
        int e = (u >> 7) & 0xFF;               // bf16 exponent field
        if (u == 0 || (e >= 116 && e <= 132)) plaus++;
    }
    flags[0] = (plaus < 128) ? 1 : 0;          // 1 => float inputs are fp32
    int nz = 0;
    for (int i = 0; i < 128; i++) if (ei[2 * i + 1] != 0) nz++;
    flags[1] = (nz < 8) ? 1 : 0;               // 1 => indices are int64
}

// ---------------- degree / norm ----------------
__global__ void k_count_deg(const int* __restrict__ ei, const int* __restrict__ flags,
                            float* __restrict__ deg) {
    int e = blockIdx.x * blockDim.x + threadIdx.x;
    if (e < N_EDGES) atomicAdd(&deg[geti(ei, (long)N_EDGES + e, flags[1])], 1.0f);
}

__global__ void k_dinv(float* __restrict__ deg) {
    int n = blockIdx.x * blockDim.x + threadIdx.x;
    if (n < N_NODES) deg[n] = rsqrtf(deg[n] + 1.0f);
}

// ---------------- input linears: [N,K] @ [K,64] + b -> fp32 [N,64] ----------------
template <int K>
__global__ __launch_bounds__(256) void k_linear_in(const void* __restrict__ in,
                                                   const void* __restrict__ w,
                                                   const void* __restrict__ b,
                                                   const int* __restrict__ flags,
                                                   float* __restrict__ out) {
    __shared__ float wl[K * 64];
    __shared__ float bl[64];
    int isf32 = flags[0];
    int tid = threadIdx.x;
    for (int i = tid; i < K * 64; i += 256) wl[i] = ldf(w, i, isf32);
    if (tid < 64) bl[tid] = ldf(b, tid, isf32);
    __syncthreads();
    int n = blockIdx.x * 4 + (tid >> 6);
    int f = tid & 63;
    if (n >= N_NODES) return;
    float acc = bl[f];
    for (int k = 0; k < K; k++) acc += ldf(in, (long)n * K + k, isf32) * wl[k * 64 + f];
    out[(long)n * 64 + f] = acc;
}

// fp32 ws input, K=64, no bias (GCN: sw = s @ gcn_w)
__global__ __launch_bounds__(256) void k_linear_f32_64(const float* __restrict__ in,
                                                       const void* __restrict__ w,
                                                       const int* __restrict__ flags,
                                                       float* __restrict__ out) {
    __shared__ float wl[64 * 64];
    int isf32 = flags[0];
    int tid = threadIdx.x;
    for (int i = tid; i < 64 * 64; i += 256) wl[i] = ldf(w, i, isf32);
    __syncthreads();
    int n = blockIdx.x * 4 + (tid >> 6);
    int f = tid & 63;
    if (n >= N_NODES) return;
    float acc = 0.f;
    const float* row = in + (long)n * 64;
    for (int k = 0; k < 64; k++) acc += row[k] * wl[k * 64 + f];
    out[(long)n * 64 + f] = acc;
}

// ---------------- GIN scatter: agg[col] += concat(x,s)[row] ----------------
__global__ void k_scatter_gin(const int* __restrict__ ei, const int* __restrict__ flags,
                              const float* __restrict__ x, const float* __restrict__ s,
                              float* __restrict__ agg) {
    long t = (long)blockIdx.x * blockDim.x + threadIdx.x;
    if (t >= (long)N_EDGES * 32) return;
    int e = (int)(t >> 5);
    int c = (int)(t & 31);                     // 4-float chunk over 128 feats
    int i64 = flags[1];
    int r  = geti(ei, e, i64);
    int co = geti(ei, (long)N_EDGES + e, i64);
    const float* src = (c < 16) ? (x + (long)r * 64 + c * 4)
                                : (s + (long)r * 64 + (c - 16) * 4);
    float4 v = *(const float4*)src;
    float* dst = agg + (long)co * 128 + c * 4;
    atomicAdd(dst + 0, v.x);
    atomicAdd(dst + 1, v.y);
    atomicAdd(dst + 2, v.z);
    atomicAdd(dst + 3, v.w);
}

// fused GIN MLP, in-place x update:
// x[n] = relu( relu((concat(x,s)[n]+agg[n]) @ w1 + b1) @ w2 + b2 )
__global__ __launch_bounds__(256) void k_gin_mlp(float* __restrict__ x,
                                                 const float* __restrict__ s,
                                                 const float* __restrict__ agg,
                                                 const void* __restrict__ w1,
                                                 const void* __restrict__ b1,
                                                 const void* __restrict__ w2,
                                                 const void* __restrict__ b2,
                                                 const int* __restrict__ flags) {
    __shared__ float w1l[128 * 64];
    __shared__ float w2l[64 * 64];
    __shared__ float b1l[64], b2l[64];
    __shared__ float hid[4][64];
    int isf32 = flags[0];
    int tid = threadIdx.x;
    for (int i = tid; i < 128 * 64; i += 256) w1l[i] = ldf(w1, i, isf32);
    for (int i = tid; i < 64 * 64; i += 256) w2l[i] = ldf(w2, i, isf32);
    if (tid < 64) { b1l[tid] = ldf(b1, tid, isf32); b2l[tid] = ldf(b2, tid, isf32); }
    __syncthreads();
    int n = blockIdx.x * 4 + (tid >> 6);
    int f = tid & 63;
    bool valid = (n < N_NODES);
    if (valid) {
        float acc = b1l[f];
        const float* xr = x + (long)n * 64;
        const float* sr = s + (long)n * 64;
        const float* ar = agg + (long)n * 128;
        for (int k = 0; k < 64; k++) acc += (xr[k] + ar[k]) * w1l[k * 64 + f];
        for (int k = 0; k < 64; k++) acc += (sr[k] + ar[64 + k]) * w1l[(64 + k) * 64 + f];
        hid[tid >> 6][f] = fmaxf(acc, 0.f);
    }
    __syncthreads();   // all x reads complete before in-place write below
    if (valid) {
        float o = b2l[f];
        const float* hv = hid[tid >> 6];
        for (int j = 0; j < 64; j++) o += hv[j] * w2l[j * 64 + f];
        x[(long)n * 64 + f] = fmaxf(o, 0.f);
    }
}

// ---------------- GCN scatter: s_agg[col] += norm * sw[row] ----------------
__global__ void k_scatter_gcn(const int* __restrict__ ei, const int* __restrict__ flags,
                              const float* __restrict__ dinv,
                              const float* __restrict__ sw, float* __restrict__ s_agg) {
    long t = (long)blockIdx.x * blockDim.x + threadIdx.x;
    if (t >= (long)N_EDGES * 16) return;
    int e = (int)(t >> 4);
    int c = (int)(t & 15);
    int i64 = flags[1];
    int r  = geti(ei, e, i64);
    int co = geti(ei, (long)N_EDGES + e, i64);
    float norm = dinv[r] * dinv[co];
    float4 v = *(const float4*)(sw + (long)r * 64 + c * 4);
    float* dst = s_agg + (long)co * 64 + c * 4;
    atomicAdd(dst + 0, norm * v.x);
    atomicAdd(dst + 1, norm * v.y);
    atomicAdd(dst + 2, norm * v.z);
    atomicAdd(dst + 3, norm * v.w);
}

// s = tanh(s_agg + dinv^2 * sw + b)   (in-place into s; element-wise, safe)
__global__ void k_gcn_combine(const float* __restrict__ s_agg, const float* __restrict__ sw,
                              const float* __restrict__ dinv, const void* __restrict__ b,
                              const int* __restrict__ flags, float* __restrict__ s) {
    long t = (long)blockIdx.x * blockDim.x + threadIdx.x;
    if (t >= (long)N_NODES * 64) return;
    int n = (int)(t >> 6);
    int f = (int)(t & 63);
    float dn = dinv[n];
    s[t] = tanhf(s_agg[t] + dn * dn * sw[t] + ldf(b, f, flags[0]));
}

// ---------------- head ----------------
__global__ __launch_bounds__(256) void k_whp(const float* __restrict__ x,
                                             const float* __restrict__ s,
                                             const void* __restrict__ w,
                                             const void* __restrict__ b,
                                             const int* __restrict__ flags,
                                             float* __restrict__ out) {
    __shared__ float wl[128 * 64];
    __shared__ float bl[64];
    int isf32 = flags[0];
    int tid = threadIdx.x;
    for (int i = tid; i < 128 * 64; i += 256) wl[i] = ldf(w, i, isf32);
    if (tid < 64) bl[tid] = ldf(b, tid, isf32);
    __syncthreads();
    int n = blockIdx.x * 4 + (tid >> 6);
    int f = tid & 63;
    if (n >= N_NODES) return;
    float acc = bl[f];
    const float* xr = x + (long)n * 64;
    const float* sr = s + (long)n * 64;
    for (int k = 0; k < 64; k++) acc += xr[k] * wl[k * 64 + f];
    for (int k = 0; k < 64; k++) acc += sr[k] * wl[(64 + k) * 64 + f];
    out[(long)n * 64 + f] = acc;
}

__global__ void k_pool(const float* __restrict__ xw, const int* __restrict__ batch,
                       const int* __restrict__ flags, float* __restrict__ xp) {
    long t = (long)blockIdx.x * blockDim.x + threadIdx.x;
    if (t >= (long)N_NODES * 64) return;
    int n = (int)(t >> 6);
    int f = (int)(t & 63);
    atomicAdd(&xp[(long)geti(batch, n, flags[1]) * 64 + f], xw[t]);
}

// per-graph: xp2 = relu(xp@post_w+post_b); y = log_softmax(xp2@ro_w+ro_b)
__global__ __launch_bounds__(64) void k_final(const float* __restrict__ xp,
                                              const void* __restrict__ post_w,
                                              const void* __restrict__ post_b,
                                              const void* __restrict__ ro_w,
                                              const void* __restrict__ ro_b,
                                              const int* __restrict__ flags,
                                              void* __restrict__ out) {
    __shared__ float xr[64];
    __shared__ float h2[64];
    __shared__ float lg[16];
    int isf32 = flags[0];
    int g = blockIdx.x;
    int f = threadIdx.x;  // 64 threads
    xr[f] = xp[(long)g * 64 + f];
    __syncthreads();
    float acc = ldf(post_b, f, isf32);
    for (int j = 0; j < 64; j++) acc += xr[j] * ldf(post_w, j * 64 + f, isf32);
    float v = fmaxf(acc, 0.f);
    h2[f] = v;
    long oxp = (long)g * 64 + f;
    if (isf32) ((float*)out)[oxp] = v; else ((bf16*)out)[oxp] = f2b(v);
    __syncthreads();
    if (f < 16) {
        float a = ldf(ro_b, f, isf32);
        for (int j = 0; j < 64; j++) a += h2[j] * ldf(ro_w, j * 16 + f, isf32);
        lg[f] = a;
    }
    __syncthreads();
    if (f < 16) {
        float m = -1e30f;
        for (int j = 0; j < 16; j++) m = fmaxf(m, lg[j]);
        float sum = 0.f;
        for (int j = 0; j < 16; j++) sum += expf(lg[j] - m);
        long oy = (long)N_GRAPHS * 64 + (long)g * 16 + f;
        float yv = lg[f] - m - logf(sum);
        if (isf32) ((float*)out)[oy] = yv; else ((bf16*)out)[oy] = f2b(yv);
    }
}

extern "C" void kernel_launch(void* const* d_in, const int* in_sizes, int n_in,
                              void* d_out, int out_size, void* d_ws, size_t ws_size,
                              hipStream_t stream) {
    const void* x_in  = d_in[0];
    const void* s_in  = d_in[1];
    const int*  ei    = (const int*)d_in[2];
    const int*  batch = (const int*)d_in[3];
    const void* pre_w = d_in[4];
    const void* pre_b = d_in[5];
    const void* emb_w = d_in[6];
    const void* emb_b = d_in[7];
    const void* gin_w1 = d_in[8];
    const void* gin_b1 = d_in[9];
    const void* gin_w2 = d_in[10];
    const void* gin_b2 = d_in[11];
    const void* gcn_w  = d_in[12];
    const void* gcn_b  = d_in[13];
    const void* whp_w  = d_in[14];
    const void* whp_b  = d_in[15];
    const void* post_w = d_in[16];
    const void* post_b = d_in[17];
    const void* ro_w   = d_in[18];
    const void* ro_b   = d_in[19];

    // weight element strides (elements, dtype handled by ldf)
    // layout in ws (fp32 words): flags(64) | dinv(N) | x(64N) | s(64N) | agg(128N) | xp(G*64)
    float* ws   = (float*)d_ws;
    int*   flags = (int*)d_ws;
    float* dinv = ws + 64;
    float* xA   = dinv + N_NODES;
    float* sA   = xA + (long)N_NODES * 64;
    float* agg  = sA + (long)N_NODES * 64;          // 128N; GCN reuses: sw=[0,64N), s_agg=[64N,128N)
    float* xp   = agg + (long)N_NODES * 128;

    int nb4 = (N_NODES + 3) / 4;

    k_detect<<<1, 64, 0, stream>>>(x_in, ei, flags);

    // degree -> dinv
    hipMemsetAsync(dinv, 0, N_NODES * sizeof(float), stream);
    k_count_deg<<<(N_EDGES + 255) / 256, 256, 0, stream>>>(ei, flags, dinv);
    k_dinv<<<(N_NODES + 255) / 256, 256, 0, stream>>>(dinv);

    // pre / embedding
    k_linear_in<128><<<nb4, 256, 0, stream>>>(x_in, pre_w, pre_b, flags, xA);
    k_linear_in<16><<<nb4, 256, 0, stream>>>(s_in, emb_w, emb_b, flags, sA);

    for (int l = 0; l < 2; l++) {
        // GIN
        hipMemsetAsync(agg, 0, (size_t)N_NODES * 128 * sizeof(float), stream);
        k_scatter_gin<<<(int)(((long)N_EDGES * 32 + 255) / 256), 256, 0, stream>>>(ei, flags, xA, sA, agg);
        k_gin_mlp<<<nb4, 256, 0, stream>>>(xA, sA, agg,
                                           (const char*)gin_w1 + 0, (const char*)gin_b1,
                                           (const char*)gin_w2, (const char*)gin_b2, flags);
        // advance layer weight pointers via separate launches below; use l-offset forms:
        if (l == 0) {
            // nothing extra; pointers for l=0 used above
        }
        // GCN
        float* sw    = agg;
        float* s_agg = agg + (long)N_NODES * 64;
        k_linear_f32_64<<<nb4, 256, 0, stream>>>(sA, gcn_w, flags, sw);
        hipMemsetAsync(s_agg, 0, (size_t)N_NODES * 64 * sizeof(float), stream);
        k_scatter_gcn<<<(int)(((long)N_EDGES * 16 + 255) / 256), 256, 0, stream>>>(ei, flags, dinv, sw, s_agg);
        k_gcn_combine<<<(int)(((long)N_NODES * 64 + 255) / 256), 256, 0, stream>>>(s_agg, sw, dinv, gcn_b, flags, sA);
        // bump weight pointers for layer 1 (element offsets; byte stride depends on dtype,
        // so offset via typed arithmetic inside a helper: we re-point by recomputing below)
        if (l == 0) {
            // advance: gin_w1 += 128*64 elems, gin_b1 += 64, gin_w2 += 64*64, gin_b2 += 64,
            // gcn_w += 64*64, gcn_b += 64. Element size unknown at host (2 or 4 bytes) —
            // handle by offsetting BOTH candidate widths identically: we instead pass
            // element offsets through a second set of pointers computed for each width.
        }
        if (l == 0) {
            // NOTE: actual layer-1 pointer advance handled below by swapping to _l1 pointers.
        }
        if (l == 0) {
            // replace pointers for next iteration — both dtype widths share the SAME element
            // count; we don't know byte width here, so use the max-width (fp32) offset only
            // if fp32, else bf16. Since we cannot branch on device flags here, we instead
            // launch layer 1 with explicit element-offset kernels (see below) — so break.
        }
        break;  // layer 1 launched explicitly below with offset-aware loads
    }

    // ---- layer 1 (explicit, with element offsets applied inside ldf-compatible wrappers) ----
    // We cannot compute byte offsets host-side without knowing dtype width, so pass base
    // pointers for BOTH widths: offset in elements is identical; we pre-offset assuming
    // bf16 AND fp32 and pick via flags inside kernels. Simplest: pass both pointers.
    {
        // element offsets for layer 1
        const long o_w1 = 128 * 64, o_b = 64, o_w2 = 64 * 64, o_wg = 64 * 64;
        const void* gin_w1_l1_b = (const bf16*)gin_w1 + o_w1;
        const void* gin_b1_l1_b = (const bf16*)gin_b1 + o_b;
        const void* gin_w2_l1_b = (const bf16*)gin_w2 + o_w2;
        const void* gin_b2_l1_b = (const bf16*)gin_b2 + o_b;
        const void* gcn_w_l1_b  = (const bf16*)gcn_w + o_wg;
        const void* gcn_b_l1_b  = (const bf16*)gcn_b + o_b;
        const void* gin_w1_l1_f = (const float*)gin_w1 + o_w1;
        const void* gin_b1_l1_f = (const float*)gin_b1 + o_b;
        const void* gin_w2_l1_f = (const float*)gin_w2 + o_w2;
        const void* gin_b2_l1_f = (const float*)gin_b2 + o_b;
        const void* gcn_w_l1_f  = (const float*)gcn_w + o_wg;
        const void* gcn_b_l1_f  = (const float*)gcn_b + o_b;
        // dual-pointer kernels: reuse the same kernels by selecting pointer on device is
        // not possible with single void* — so launch a tiny pointer-select? Instead:
        // k_* kernels read via ldf(w, i, isf32); we can emulate layer-1 by passing base
        // pointer and adding the element offset to i. Relaunch with index offset:
        hipMemsetAsync(agg, 0, (size_t)N_NODES * 128 * sizeof(float), stream);
        k_scatter_gin<<<(int)(((long)N_EDGES * 32 + 255) / 256), 256, 0, stream>>>(ei, flags, xA, sA, agg);
        // pass BOTH candidate pointers? Simpler: kernels take base + element offset.
        (void)gin_w1_l1_b; (void)gin_b1_l1_b; (void)gin_w2_l1_b; (void)gin_b2_l1_b;
        (void)gcn_w_l1_b; (void)gcn_b_l1_b;
        (void)gin_w1_l1_f; (void)gin_b1_l1_f; (void)gin_w2_l1_f; (void)gin_b2_l1_f;
        (void)gcn_w_l1_f; (void)gcn_b_l1_f;
    }
    // Use offset-taking variants for layer 1:
    extern void launch_layer1_tail(const void*, const void*, const void*, const void*,
                                   const void*, const void*, const int*, float*, float*,
                                   float*, const int*, hipStream_t);  // (not used)
    // --- direct offset-aware launches (kernels below accept an element offset) ---
    // (see k_gin_mlp_off / k_linear_f32_64_off / k_gcn_combine_off definitions)
    {
        // forward declarations resolved at file scope
    }
    // GIN MLP layer 1
    void k_launch_unused();
    {
        // launch with element offsets baked via extra arg
    }
    // Actual layer-1 tail:
    {
        extern __global__ void k_gin_mlp_off(float*, const float*, const float*,
                                             const void*, const void*, const void*, const void*,
                                             const int*, long, long);
        extern __global__ void k_linear_f32_64_off(const float*, const void*, const int*, float*, long);
        extern __global__ void k_gcn_combine_off(const float*, const float*, const float*,
                                                 const void*, const int*, float*, long);
        k_gin_mlp_off<<<nb4, 256, 0, stream>>>(xA, sA, agg, gin_w1, gin_b1, gin_w2, gin_b2,
                                               flags, (long)128 * 64, (long)64);
        float* sw    = agg;
        float* s_agg = agg + (long)N_NODES * 64;
        k_linear_f32_64_off<<<nb4, 256, 0, stream>>>(sA, gcn_w, flags, sw, (long)64 * 64);
        hipMemsetAsync(s_agg, 0, (size_t)N_NODES * 64 * sizeof(float), stream);
        k_scatter_gcn<<<(int)(((long)N_EDGES * 16 + 255) / 256), 256, 0, stream>>>(ei, flags, dinv, sw, s_agg);
        k_gcn_combine_off<<<(int)(((long)N_NODES * 64 + 255) / 256), 256, 0, stream>>>(s_agg, sw, dinv, gcn_b, flags, sA, (long)64);
    }

    // head
    k_whp<<<nb4, 256, 0, stream>>>(xA, sA, whp_w, whp_b, flags, agg);
    hipMemsetAsync(xp, 0, (size_t)N_GRAPHS * 64 * sizeof(float), stream);
    k_pool<<<(int)(((long)N_NODES * 64 + 255) / 256), 256, 0, stream>>>(agg, batch, flags, xp);

    k_final<<<N_GRAPHS, 64, 0, stream>>>(xp, post_w, post_b, ro_w, ro_b, flags, d_out);
}

// ---------------- offset-aware layer-1 kernels ----------------
__global__ __launch_bounds__(256) void k_gin_mlp_off(float* __restrict__ x,
                                                     const float* __restrict__ s,
                                                     const float* __restrict__ agg,
                                                     const void* __restrict__ w1,
                                                     const void* __restrict__ b1,
                                                     const void* __restrict__ w2,
                                                     const void* __restrict__ b2,
                                                     const int* __restrict__ flags,
                                                     long w_off, long b_off) {
    __shared__ float w1l[128 * 64];
    __shared__ float w2l[64 * 64];
    __shared__ float b1l[64], b2l[64];
    __shared__ float hid[4][64];
    int isf32 = flags[0];
    int tid = threadIdx.x;
    for (int i = tid; i < 128 * 64; i += 256) w1l[i] = ldf(w1, w_off + i, isf32);
    for (int i = tid; i < 64 * 64; i += 256) w2l[i] = ldf(w2, (w_off / 2) + i, isf32);
    if (tid < 64) { b1l[tid] = ldf(b1, b_off + tid, isf32); b2l[tid] = ldf(b2, b_off + tid, isf32); }
    __syncthreads();
    int n = blockIdx.x * 4 + (tid >> 6);
    int f = tid & 63;
    bool valid = (n < N_NODES);
    if (valid) {
        float acc = b1l[f];
        const float* xr = x + (long)n * 64;
        const float* sr = s + (long)n * 64;
        const float* ar = agg + (long)n * 128;
        for (int k = 0; k < 64; k++) acc += (xr[k] + ar[k]) * w1l[k * 64 + f];
        for (int k = 0; k < 64; k++) acc += (sr[k] + ar[64 + k]) * w1l[(64 + k) * 64 + f];
        hid[tid >> 6][f] = fmaxf(acc, 0.f);
    }
    __syncthreads();
    if (valid) {
        float o = b2l[f];
        const float* hv = hid[tid >> 6];
        for (int j = 0; j < 64; j++) o += hv[j] * w2l[j * 64 + f];
        x[(long)n * 64 + f] = fmaxf(o, 0.f);
    }
}

__global__ __launch_bounds__(256) void k_linear_f32_64_off(const float* __restrict__ in,
                                                           const void* __restrict__ w,
                                                           const int* __restrict__ flags,
                                                           float* __restrict__ out, long w_off) {
    __shared__ float wl[64 * 64];
    int isf32 = flags[0];
    int tid = threadIdx.x;
    for (int i = tid; i < 64 * 64; i += 256) wl[i] = ldf(w, w_off + i, isf32);
    __syncthreads();
    int n = blockIdx.x * 4 + (tid >> 6);
    int f = tid & 63;
    if (n >= N_NODES) return;
    float acc = 0.f;
    const float* row = in + (long)n * 64;
    for (int k = 0; k < 64; k++) acc += row[k] * wl[k * 64 + f];
    out[(long)n * 64 + f] = acc;
}

__global__ void k_gcn_combine_off(const float* __restrict__ s_agg, const float* __restrict__ sw,
                                  const float* __restrict__ dinv, const void* __restrict__ b,
                                  const int* __restrict__ flags, float* __restrict__ s, long b_off) {
    long t = (long)blockIdx.x * blockDim.x + threadIdx.x;
    if (t >= (long)N_NODES * 64) return;
    int n = (int)(t >> 6);
    int f = (int)(t & 63);
    float dn = dinv[n];
    s[t] = tanhf(s_agg[t] + dn * dn * sw[t] + ldf(b, b_off + f, flags[0]));
}

// Round 3
// 2984.801 us; speedup vs baseline: 3.2916x; 3.2916x over previous
//
#include <hip/hip_runtime.h>
#include <hip/hip_bf16.h>

#define N_NODES 100000
#define N_EDGES 1600000
#define N_GRAPHS 512

typedef __hip_bfloat16 bf16;

__device__ __forceinline__ float b2f(bf16 v) { return __bfloat162float(v); }
__device__ __forceinline__ bf16 f2b(float v) { return __float2bfloat16(v); }

// flag-branched input load: isf32 ? fp32 : bf16
__device__ __forceinline__ float ldf(const void* p, long i, int isf32) {
    return isf32 ? ((const float*)p)[i] : b2f(((const bf16*)p)[i]);
}
// flag-branched index load: is64 ? low word of int64 : int32
__device__ __forceinline__ int geti(const int* p, long i, int is64) {
    return is64 ? p[2 * i] : p[i];
}

// ---------------- dtype detection ----------------
__global__ void k_detect(const void* __restrict__ x, const int* __restrict__ ei,
                         int* __restrict__ flags) {
    if (threadIdx.x != 0 || blockIdx.x != 0) return;
    const unsigned short* xu = (const unsigned short*)x;
    int plaus = 0;
    for (int i = 0; i < 256; i++) {
        unsigned short u = xu[2 * i];          // even-indexed 16-bit words
        int e = (u >> 7) & 0xFF;               // bf16 exponent field
        if (u == 0 || (e >= 116 && e <= 132)) plaus++;
    }
    flags[0] = (plaus < 128) ? 1 : 0;          // 1 => float inputs are fp32
    int nz = 0;
    for (int i = 0; i < 128; i++) if (ei[2 * i + 1] != 0) nz++;
    flags[1] = (nz < 8) ? 1 : 0;               // 1 => indices are int64
}

// ---------------- degree / dinv ----------------
__global__ void k_deg(const int* __restrict__ ei, const int* __restrict__ flags,
                      int* __restrict__ deg) {
    int e = blockIdx.x * blockDim.x + threadIdx.x;
    if (e < N_EDGES) atomicAdd(&deg[geti(ei, (long)N_EDGES + e, flags[1])], 1);
}

__global__ void k_dinv(const int* __restrict__ deg, float* __restrict__ dinv) {
    int n = blockIdx.x * blockDim.x + threadIdx.x;
    if (n < N_NODES) dinv[n] = rsqrtf((float)deg[n] + 1.0f);
}

// ---------------- CSR build: scan + bucket ----------------
__global__ __launch_bounds__(256) void k_scan_block(const int* __restrict__ deg,
                                                    int* __restrict__ excl,
                                                    int* __restrict__ bsum) {
    __shared__ int tmp[256];
    int tid = threadIdx.x;
    int i = blockIdx.x * 256 + tid;
    int v = (i < N_NODES) ? deg[i] : 0;
    tmp[tid] = v;
    __syncthreads();
    for (int off = 1; off < 256; off <<= 1) {
        int t = (tid >= off) ? tmp[tid - off] : 0;
        __syncthreads();
        tmp[tid] += t;
        __syncthreads();
    }
    if (i < N_NODES) excl[i] = tmp[tid] - v;   // block-local exclusive
    if (tid == 255) bsum[blockIdx.x] = tmp[255];
}

__global__ __launch_bounds__(512) void k_scan_bsum(int* __restrict__ bsum, int nb) {
    __shared__ int tmp[512];
    int tid = threadIdx.x;
    int v = (tid < nb) ? bsum[tid] : 0;
    tmp[tid] = v;
    __syncthreads();
    for (int off = 1; off < 512; off <<= 1) {
        int t = (tid >= off) ? tmp[tid - off] : 0;
        __syncthreads();
        tmp[tid] += t;
        __syncthreads();
    }
    if (tid < nb) bsum[tid] = tmp[tid] - v;    // exclusive
}

__global__ void k_scan_add(int* __restrict__ excl, const int* __restrict__ bsum) {
    int i = blockIdx.x * 256 + threadIdx.x;
    if (i < N_NODES) excl[i] += bsum[blockIdx.x];   // now global exclusive starts
}

// bucket edges; row_pos mutates from starts to ends
__global__ void k_build_csr(const int* __restrict__ ei, const int* __restrict__ flags,
                            int* __restrict__ row_pos, int* __restrict__ csr_src) {
    int e = blockIdx.x * blockDim.x + threadIdx.x;
    if (e >= N_EDGES) return;
    int i64 = flags[1];
    int r = geti(ei, e, i64);
    int c = geti(ei, (long)N_EDGES + e, i64);
    int pos = atomicAdd(&row_pos[c], 1);
    csr_src[pos] = r;
}

// ---------------- input linears: [N,K] @ [K,64] + b -> fp32 [N,64] ----------------
template <int K>
__global__ __launch_bounds__(256) void k_linear_in(const void* __restrict__ in,
                                                   const void* __restrict__ w,
                                                   const void* __restrict__ b,
                                                   const int* __restrict__ flags,
                                                   float* __restrict__ out) {
    __shared__ float wl[K * 64];
    __shared__ float bl[64];
    int isf32 = flags[0];
    int tid = threadIdx.x;
    for (int i = tid; i < K * 64; i += 256) wl[i] = ldf(w, i, isf32);
    if (tid < 64) bl[tid] = ldf(b, tid, isf32);
    __syncthreads();
    int n = blockIdx.x * 4 + (tid >> 6);
    int f = tid & 63;
    if (n >= N_NODES) return;
    float acc = bl[f];
    if (isf32) {
        const float* row = (const float*)in + (long)n * K;
        for (int k = 0; k < K; k++) acc += row[k] * wl[k * 64 + f];
    } else {
        const bf16* row = (const bf16*)in + (long)n * K;
        for (int k = 0; k < K; k++) acc += b2f(row[k]) * wl[k * 64 + f];
    }
    out[(long)n * 64 + f] = acc;
}

// GCN linear: sw = s @ gcn_w (fp32 in ws), weight element offset for layer
__global__ __launch_bounds__(256) void k_linear_gcn(const float* __restrict__ in,
                                                    const void* __restrict__ w,
                                                    const int* __restrict__ flags,
                                                    float* __restrict__ out, long w_off) {
    __shared__ float wl[64 * 64];
    int isf32 = flags[0];
    int tid = threadIdx.x;
    for (int i = tid; i < 64 * 64; i += 256) wl[i] = ldf(w, w_off + i, isf32);
    __syncthreads();
    int n = blockIdx.x * 4 + (tid >> 6);
    int f = tid & 63;
    if (n >= N_NODES) return;
    float acc = 0.f;
    const float* row = in + (long)n * 64;
    for (int k = 0; k < 64; k++) acc += row[k] * wl[k * 64 + f];
    out[(long)n * 64 + f] = acc;
}

// ---------------- fused GIN: gather + (h+agg) MLP ----------------
// xout[n] = relu( relu((concat(x,s)[n] + sum_nb concat(x,s)[src]) @ w1 + b1) @ w2 + b2 )
__global__ __launch_bounds__(256) void k_gin_fused(const float* __restrict__ x,
                                                   const float* __restrict__ s,
                                                   const int* __restrict__ row_end,
                                                   const int* __restrict__ deg,
                                                   const int* __restrict__ csr_src,
                                                   const void* __restrict__ w1,
                                                   const void* __restrict__ b1,
                                                   const void* __restrict__ w2,
                                                   const void* __restrict__ b2,
                                                   const int* __restrict__ flags,
                                                   long w1_off, long b_off, long w2_off,
                                                   float* __restrict__ xout) {
    __shared__ float w1l[128 * 64];
    __shared__ float w2l[64 * 64];
    __shared__ float b1l[64], b2l[64];
    __shared__ float hbuf[4][128];
    __shared__ float hid[4][64];
    int isf32 = flags[0];
    int tid = threadIdx.x;
    for (int i = tid; i < 128 * 64; i += 256) w1l[i] = ldf(w1, w1_off + i, isf32);
    for (int i = tid; i < 64 * 64; i += 256) w2l[i] = ldf(w2, w2_off + i, isf32);
    if (tid < 64) { b1l[tid] = ldf(b1, b_off + tid, isf32); b2l[tid] = ldf(b2, b_off + tid, isf32); }

    int slot = tid >> 6;
    int lane = tid & 63;
    int n = blockIdx.x * 4 + slot;
    bool valid = (n < N_NODES);
    if (valid) {
        int end = row_end[n];
        int beg = end - deg[n];
        float a0 = x[(long)n * 64 + lane];
        float a1 = s[(long)n * 64 + lane];
        for (int p = beg; p < end; p++) {
            int src = csr_src[p];
            a0 += x[(long)src * 64 + lane];
            a1 += s[(long)src * 64 + lane];
        }
        hbuf[slot][lane] = a0;
        hbuf[slot][64 + lane] = a1;
    }
    __syncthreads();
    if (valid) {
        float acc = b1l[lane];
        const float* hv = hbuf[slot];
        for (int k = 0; k < 128; k++) acc += hv[k] * w1l[k * 64 + lane];
        hid[slot][lane] = fmaxf(acc, 0.f);
    }
    __syncthreads();
    if (valid) {
        float o = b2l[lane];
        const float* hv = hid[slot];
        for (int j = 0; j < 64; j++) o += hv[j] * w2l[j * 64 + lane];
        xout[(long)n * 64 + lane] = fmaxf(o, 0.f);
    }
}

// ---------------- fused GCN: gather + self term + tanh ----------------
// s[n] = tanh( dinv[n]*sum_nb dinv[src]*sw[src] + dinv[n]^2*sw[n] + b )
__global__ __launch_bounds__(256) void k_gcn_gather(const int* __restrict__ row_end,
                                                    const int* __restrict__ deg,
                                                    const int* __restrict__ csr_src,
                                                    const float* __restrict__ dinv,
                                                    const float* __restrict__ sw,
                                                    const void* __restrict__ b,
                                                    const int* __restrict__ flags,
                                                    long b_off,
                                                    float* __restrict__ s) {
    int tid = threadIdx.x;
    int slot = tid >> 6;
    int lane = tid & 63;
    int n = blockIdx.x * 4 + slot;
    if (n >= N_NODES) return;
    int end = row_end[n];
    int beg = end - deg[n];
    float acc = 0.f;
    for (int p = beg; p < end; p++) {
        int src = csr_src[p];
        acc += dinv[src] * sw[(long)src * 64 + lane];
    }
    float dn = dinv[n];
    float self = sw[(long)n * 64 + lane];
    s[(long)n * 64 + lane] = tanhf(dn * acc + dn * dn * self + ldf(b, b_off + lane, flags[0]));
}

// ---------------- head ----------------
__global__ __launch_bounds__(256) void k_whp(const float* __restrict__ x,
                                             const float* __restrict__ s,
                                             const void* __restrict__ w,
                                             const void* __restrict__ b,
                                             const int* __restrict__ flags,
                                             float* __restrict__ out) {
    __shared__ float wl[128 * 64];
    __shared__ float bl[64];
    int isf32 = flags[0];
    int tid = threadIdx.x;
    for (int i = tid; i < 128 * 64; i += 256) wl[i] = ldf(w, i, isf32);
    if (tid < 64) bl[tid] = ldf(b, tid, isf32);
    __syncthreads();
    int n = blockIdx.x * 4 + (tid >> 6);
    int f = tid & 63;
    if (n >= N_NODES) return;
    float acc = bl[f];
    const float* xr = x + (long)n * 64;
    const float* sr = s + (long)n * 64;
    for (int k = 0; k < 64; k++) acc += xr[k] * wl[k * 64 + f];
    for (int k = 0; k < 64; k++) acc += sr[k] * wl[(64 + k) * 64 + f];
    out[(long)n * 64 + f] = acc;
}

__global__ void k_pool(const float* __restrict__ xw, const int* __restrict__ batch,
                       const int* __restrict__ flags, float* __restrict__ xp) {
    long t = (long)blockIdx.x * blockDim.x + threadIdx.x;
    if (t >= (long)N_NODES * 64) return;
    int n = (int)(t >> 6);
    int f = (int)(t & 63);
    atomicAdd(&xp[(long)geti(batch, n, flags[1]) * 64 + f], xw[t]);
}

__global__ __launch_bounds__(64) void k_final(const float* __restrict__ xp,
                                              const void* __restrict__ post_w,
                                              const void* __restrict__ post_b,
                                              const void* __restrict__ ro_w,
                                              const void* __restrict__ ro_b,
                                              const int* __restrict__ flags,
                                              void* __restrict__ out) {
    __shared__ float xr[64];
    __shared__ float h2[64];
    __shared__ float lg[16];
    int isf32 = flags[0];
    int g = blockIdx.x;
    int f = threadIdx.x;  // 64 threads
    xr[f] = xp[(long)g * 64 + f];
    __syncthreads();
    float acc = ldf(post_b, f, isf32);
    for (int j = 0; j < 64; j++) acc += xr[j] * ldf(post_w, j * 64 + f, isf32);
    float v = fmaxf(acc, 0.f);
    h2[f] = v;
    long oxp = (long)g * 64 + f;
    if (isf32) ((float*)out)[oxp] = v; else ((bf16*)out)[oxp] = f2b(v);
    __syncthreads();
    if (f < 16) {
        float a = ldf(ro_b, f, isf32);
        for (int j = 0; j < 64; j++) a += h2[j] * ldf(ro_w, j * 16 + f, isf32);
        lg[f] = a;
    }
    __syncthreads();
    if (f < 16) {
        float m = -1e30f;
        for (int j = 0; j < 16; j++) m = fmaxf(m, lg[j]);
        float sum = 0.f;
        for (int j = 0; j < 16; j++) sum += expf(lg[j] - m);
        long oy = (long)N_GRAPHS * 64 + (long)g * 16 + f;
        float yv = lg[f] - m - logf(sum);
        if (isf32) ((float*)out)[oy] = yv; else ((bf16*)out)[oy] = f2b(yv);
    }
}

extern "C" void kernel_launch(void* const* d_in, const int* in_sizes, int n_in,
                              void* d_out, int out_size, void* d_ws, size_t ws_size,
                              hipStream_t stream) {
    const void* x_in  = d_in[0];
    const void* s_in  = d_in[1];
    const int*  ei    = (const int*)d_in[2];
    const int*  batch = (const int*)d_in[3];
    const void* pre_w = d_in[4];
    const void* pre_b = d_in[5];
    const void* emb_w = d_in[6];
    const void* emb_b = d_in[7];
    const void* gin_w1 = d_in[8];
    const void* gin_b1 = d_in[9];
    const void* gin_w2 = d_in[10];
    const void* gin_b2 = d_in[11];
    const void* gcn_w  = d_in[12];
    const void* gcn_b  = d_in[13];
    const void* whp_w  = d_in[14];
    const void* whp_b  = d_in[15];
    const void* post_w = d_in[16];
    const void* post_b = d_in[17];
    const void* ro_w   = d_in[18];
    const void* ro_b   = d_in[19];

    // ws layout (32-bit words):
    // flags(64) | deg(N) | row_end(N) | bsum(512) | csr_src(E) | dinv(N)
    // | x0(64N) | x1(64N) | s(64N) | sw(64N) | xp(G*64)
    int* flags   = (int*)d_ws;
    int* deg     = flags + 64;
    int* row_pos = deg + N_NODES;                 // starts, then mutates to ends
    int* bsum    = row_pos + N_NODES;
    int* csr_src = bsum + 512;
    float* dinv  = (float*)(csr_src + N_EDGES);
    float* x0    = dinv + N_NODES;
    float* x1    = x0 + (long)N_NODES * 64;
    float* sA    = x1 + (long)N_NODES * 64;
    float* sw    = sA + (long)N_NODES * 64;
    float* xp    = sw + (long)N_NODES * 64;

    const int nb4 = (N_NODES + 3) / 4;            // 25000
    const int nbN = (N_NODES + 255) / 256;        // 391
    const int nbE = (N_EDGES + 255) / 256;

    k_detect<<<1, 64, 0, stream>>>(x_in, ei, flags);

    // CSR build + dinv
    hipMemsetAsync(deg, 0, N_NODES * sizeof(int), stream);
    k_deg<<<nbE, 256, 0, stream>>>(ei, flags, deg);
    k_dinv<<<nbN, 256, 0, stream>>>(deg, dinv);
    k_scan_block<<<nbN, 256, 0, stream>>>(deg, row_pos, bsum);
    k_scan_bsum<<<1, 512, 0, stream>>>(bsum, nbN);
    k_scan_add<<<nbN, 256, 0, stream>>>(row_pos, bsum);
    k_build_csr<<<nbE, 256, 0, stream>>>(ei, flags, row_pos, csr_src);  // row_pos -> ends

    // pre / embedding
    k_linear_in<128><<<nb4, 256, 0, stream>>>(x_in, pre_w, pre_b, flags, x0);
    k_linear_in<16><<<nb4, 256, 0, stream>>>(s_in, emb_w, emb_b, flags, sA);

    // layer 0: x0 -> x1
    k_gin_fused<<<nb4, 256, 0, stream>>>(x0, sA, row_pos, deg, csr_src,
                                         gin_w1, gin_b1, gin_w2, gin_b2, flags,
                                         0L, 0L, 0L, x1);
    k_linear_gcn<<<nb4, 256, 0, stream>>>(sA, gcn_w, flags, sw, 0L);
    k_gcn_gather<<<nb4, 256, 0, stream>>>(row_pos, deg, csr_src, dinv, sw, gcn_b, flags, 0L, sA);

    // layer 1: x1 -> x0
    k_gin_fused<<<nb4, 256, 0, stream>>>(x1, sA, row_pos, deg, csr_src,
                                         gin_w1, gin_b1, gin_w2, gin_b2, flags,
                                         (long)128 * 64, 64L, (long)64 * 64, x0);
    k_linear_gcn<<<nb4, 256, 0, stream>>>(sA, gcn_w, flags, sw, (long)64 * 64);
    k_gcn_gather<<<nb4, 256, 0, stream>>>(row_pos, deg, csr_src, dinv, sw, gcn_b, flags, 64L, sA);

    // head
    k_whp<<<nb4, 256, 0, stream>>>(x0, sA, whp_w, whp_b, flags, sw);
    hipMemsetAsync(xp, 0, (size_t)N_GRAPHS * 64 * sizeof(float), stream);
    k_pool<<<(int)(((long)N_NODES * 64 + 255) / 256), 256, 0, stream>>>(sw, batch, flags, xp);

    k_final<<<N_GRAPHS, 64, 0, stream>>>(xp, post_w, post_b, ro_w, ro_b, flags, d_out);
}

// Round 4
// 1757.619 us; speedup vs baseline: 5.5898x; 1.6982x over previous
//
#include <hip/hip_runtime.h>
#include <hip/hip_bf16.h>

#define N_NODES 100000
#define N_EDGES 1600000
#define N_GRAPHS 512
#define NBGS 2048   // grid-stride block count for node-parallel kernels

typedef __hip_bfloat16 bf16;

__device__ __forceinline__ float b2f(bf16 v) { return __bfloat162float(v); }
__device__ __forceinline__ bf16 f2b(float v) { return __float2bfloat16(v); }

__device__ __forceinline__ float ldf(const void* p, long i, int isf32) {
    return isf32 ? ((const float*)p)[i] : b2f(((const bf16*)p)[i]);
}
__device__ __forceinline__ int geti(const int* p, long i, int is64) {
    return is64 ? p[2 * i] : p[i];
}

// ---------------- dtype detection ----------------
__global__ void k_detect(const void* __restrict__ x, const int* __restrict__ ei,
                         int* __restrict__ flags) {
    if (threadIdx.x != 0 || blockIdx.x != 0) return;
    const unsigned short* xu = (const unsigned short*)x;
    int plaus = 0;
    for (int i = 0; i < 256; i++) {
        unsigned short u = xu[2 * i];
        int e = (u >> 7) & 0xFF;
        if (u == 0 || (e >= 116 && e <= 132)) plaus++;
    }
    flags[0] = (plaus < 128) ? 1 : 0;          // 1 => fp32 inputs
    int nz = 0;
    for (int i = 0; i < 128; i++) if (ei[2 * i + 1] != 0) nz++;
    flags[1] = (nz < 8) ? 1 : 0;               // 1 => int64 indices
}

// ---------------- degree / dinv ----------------
__global__ void k_deg(const int* __restrict__ ei, const int* __restrict__ flags,
                      int* __restrict__ deg) {
    int e = blockIdx.x * blockDim.x + threadIdx.x;
    if (e < N_EDGES) atomicAdd(&deg[geti(ei, (long)N_EDGES + e, flags[1])], 1);
}

__global__ void k_dinv(const int* __restrict__ deg, float* __restrict__ dinv) {
    int n = blockIdx.x * blockDim.x + threadIdx.x;
    if (n < N_NODES) dinv[n] = rsqrtf((float)deg[n] + 1.0f);
}

// ---------------- CSR build ----------------
__global__ __launch_bounds__(256) void k_scan_block(const int* __restrict__ deg,
                                                    int* __restrict__ excl,
                                                    int* __restrict__ bsum) {
    __shared__ int tmp[256];
    int tid = threadIdx.x;
    int i = blockIdx.x * 256 + tid;
    int v = (i < N_NODES) ? deg[i] : 0;
    tmp[tid] = v;
    __syncthreads();
    for (int off = 1; off < 256; off <<= 1) {
        int t = (tid >= off) ? tmp[tid - off] : 0;
        __syncthreads();
        tmp[tid] += t;
        __syncthreads();
    }
    if (i < N_NODES) excl[i] = tmp[tid] - v;
    if (tid == 255) bsum[blockIdx.x] = tmp[255];
}

__global__ __launch_bounds__(512) void k_scan_bsum(int* __restrict__ bsum, int nb) {
    __shared__ int tmp[512];
    int tid = threadIdx.x;
    int v = (tid < nb) ? bsum[tid] : 0;
    tmp[tid] = v;
    __syncthreads();
    for (int off = 1; off < 512; off <<= 1) {
        int t = (tid >= off) ? tmp[tid - off] : 0;
        __syncthreads();
        tmp[tid] += t;
        __syncthreads();
    }
    if (tid < nb) bsum[tid] = tmp[tid] - v;
}

__global__ void k_scan_add(int* __restrict__ excl, const int* __restrict__ bsum) {
    int i = blockIdx.x * 256 + threadIdx.x;
    if (i < N_NODES) excl[i] += bsum[blockIdx.x];
}

__global__ void k_build_csr(const int* __restrict__ ei, const int* __restrict__ flags,
                            int* __restrict__ row_pos, int* __restrict__ csr_src) {
    int e = blockIdx.x * blockDim.x + threadIdx.x;
    if (e >= N_EDGES) return;
    int i64 = flags[1];
    int r = geti(ei, e, i64);
    int c = geti(ei, (long)N_EDGES + e, i64);
    int pos = atomicAdd(&row_pos[c], 1);
    csr_src[pos] = r;
}

// ---------------- pre: x_in[N,128] @ pre_w + b -> x0 ----------------
__global__ __launch_bounds__(256) void k_pre(const void* __restrict__ in,
                                             const void* __restrict__ w,
                                             const void* __restrict__ b,
                                             const int* __restrict__ flags,
                                             float* __restrict__ out) {
    __shared__ float wl[128 * 64];
    __shared__ float bl[64];
    int isf32 = flags[0];
    int tid = threadIdx.x;
    for (int i = tid; i < 128 * 64; i += 256) wl[i] = ldf(w, i, isf32);
    if (tid < 64) bl[tid] = ldf(b, tid, isf32);
    __syncthreads();
    int slot = tid >> 6, lane = tid & 63;
    for (int n0 = blockIdx.x * 4; n0 < N_NODES; n0 += NBGS * 4) {
        int n = n0 + slot;
        if (n >= N_NODES) continue;
        float r0 = ldf(in, (long)n * 128 + lane, isf32);
        float r1 = ldf(in, (long)n * 128 + 64 + lane, isf32);
        float acc = bl[lane];
        #pragma unroll
        for (int k = 0; k < 64; k++) {
            acc += __shfl(r0, k) * wl[k * 64 + lane];
            acc += __shfl(r1, k) * wl[(64 + k) * 64 + lane];
        }
        out[(long)n * 64 + lane] = acc;
    }
}

// ---------------- emb: s_in[N,16] @ emb_w + b -> sA ----------------
__global__ __launch_bounds__(256) void k_emb(const void* __restrict__ in,
                                             const void* __restrict__ w,
                                             const void* __restrict__ b,
                                             const int* __restrict__ flags,
                                             float* __restrict__ out) {
    __shared__ float wl[16 * 64];
    __shared__ float bl[64];
    int isf32 = flags[0];
    int tid = threadIdx.x;
    for (int i = tid; i < 16 * 64; i += 256) wl[i] = ldf(w, i, isf32);
    if (tid < 64) bl[tid] = ldf(b, tid, isf32);
    __syncthreads();
    int slot = tid >> 6, lane = tid & 63;
    for (int n0 = blockIdx.x * 4; n0 < N_NODES; n0 += NBGS * 4) {
        int n = n0 + slot;
        if (n >= N_NODES) continue;
        float r = (lane < 16) ? ldf(in, (long)n * 16 + lane, isf32) : 0.f;
        float acc = bl[lane];
        #pragma unroll
        for (int k = 0; k < 16; k++) acc += __shfl(r, k) * wl[k * 64 + lane];
        out[(long)n * 64 + lane] = acc;
    }
}

// ---------------- 128->64 linear on ws buffers (z precompute & whp) ----------------
__global__ __launch_bounds__(256) void k_linear128(const float* __restrict__ x,
                                                   const float* __restrict__ s,
                                                   const void* __restrict__ w,
                                                   const void* __restrict__ b,
                                                   const int* __restrict__ flags,
                                                   long w_off, long b_off, int use_bias,
                                                   float* __restrict__ out) {
    __shared__ float wl[128 * 64];
    __shared__ float bl[64];
    int isf32 = flags[0];
    int tid = threadIdx.x;
    for (int i = tid; i < 128 * 64; i += 256) wl[i] = ldf(w, w_off + i, isf32);
    if (tid < 64) bl[tid] = use_bias ? ldf(b, b_off + tid, isf32) : 0.f;
    __syncthreads();
    int slot = tid >> 6, lane = tid & 63;
    for (int n0 = blockIdx.x * 4; n0 < N_NODES; n0 += NBGS * 4) {
        int n = n0 + slot;
        if (n >= N_NODES) continue;
        float xk = x[(long)n * 64 + lane];
        float sk = s[(long)n * 64 + lane];
        float acc = bl[lane];
        #pragma unroll
        for (int k = 0; k < 64; k++) {
            acc += __shfl(xk, k) * wl[k * 64 + lane];
            acc += __shfl(sk, k) * wl[(64 + k) * 64 + lane];
        }
        out[(long)n * 64 + lane] = acc;
    }
}

// ---------------- GCN linear, pre-scaled: swd = dinv[n] * (s @ gcn_w) ----------------
__global__ __launch_bounds__(256) void k_linear_gcn(const float* __restrict__ s,
                                                    const float* __restrict__ dinv,
                                                    const void* __restrict__ w,
                                                    const int* __restrict__ flags,
                                                    long w_off,
                                                    float* __restrict__ out) {
    __shared__ float wl[64 * 64];
    int isf32 = flags[0];
    int tid = threadIdx.x;
    for (int i = tid; i < 64 * 64; i += 256) wl[i] = ldf(w, w_off + i, isf32);
    __syncthreads();
    int slot = tid >> 6, lane = tid & 63;
    for (int n0 = blockIdx.x * 4; n0 < N_NODES; n0 += NBGS * 4) {
        int n = n0 + slot;
        if (n >= N_NODES) continue;
        float sk = s[(long)n * 64 + lane];
        float acc = 0.f;
        #pragma unroll
        for (int k = 0; k < 64; k++) acc += __shfl(sk, k) * wl[k * 64 + lane];
        out[(long)n * 64 + lane] = dinv[n] * acc;
    }
}

// ---------------- fused GIN gather + 2nd MLP layer ----------------
// zsum[n] = z[n] + sum_nb z[src]; hid = relu(zsum + b1); xout = relu(hid @ w2 + b2)
__global__ __launch_bounds__(256) void k_gin_gather(const float* __restrict__ z,
                                                    const int* __restrict__ row_end,
                                                    const int* __restrict__ deg,
                                                    const int* __restrict__ csr_src,
                                                    const void* __restrict__ w2,
                                                    const void* __restrict__ b1,
                                                    const void* __restrict__ b2,
                                                    const int* __restrict__ flags,
                                                    long w2_off, long b_off,
                                                    float* __restrict__ xout) {
    __shared__ float w2l[64 * 64];
    int isf32 = flags[0];
    int tid = threadIdx.x;
    for (int i = tid; i < 64 * 64; i += 256) w2l[i] = ldf(w2, w2_off + i, isf32);
    __syncthreads();
    int slot = tid >> 6, lane = tid & 63;
    float b1l = ldf(b1, b_off + lane, isf32);
    float b2l = ldf(b2, b_off + lane, isf32);
    for (int n0 = blockIdx.x * 4; n0 < N_NODES; n0 += NBGS * 4) {
        int n = n0 + slot;
        if (n >= N_NODES) continue;
        int end = row_end[n];
        int beg = end - deg[n];
        float acc = z[(long)n * 64 + lane];
        int p = beg;
        for (; p + 4 <= end; p += 4) {
            int i0 = csr_src[p], i1 = csr_src[p + 1], i2 = csr_src[p + 2], i3 = csr_src[p + 3];
            float v0 = z[(long)i0 * 64 + lane];
            float v1 = z[(long)i1 * 64 + lane];
            float v2 = z[(long)i2 * 64 + lane];
            float v3 = z[(long)i3 * 64 + lane];
            acc += (v0 + v1) + (v2 + v3);
        }
        for (; p < end; p++) acc += z[(long)csr_src[p] * 64 + lane];
        float h = fmaxf(acc + b1l, 0.f);
        float o = b2l;
        #pragma unroll
        for (int j = 0; j < 64; j++) o += __shfl(h, j) * w2l[j * 64 + lane];
        xout[(long)n * 64 + lane] = fmaxf(o, 0.f);
    }
}

// ---------------- fused GCN gather + tanh ----------------
// s[n] = tanh( dinv[n] * (swd[n] + sum_nb swd[src]) + b )
__global__ __launch_bounds__(256) void k_gcn_gather(const float* __restrict__ swd,
                                                    const int* __restrict__ row_end,
                                                    const int* __restrict__ deg,
                                                    const int* __restrict__ csr_src,
                                                    const float* __restrict__ dinv,
                                                    const void* __restrict__ b,
                                                    const int* __restrict__ flags,
                                                    long b_off,
                                                    float* __restrict__ s) {
    int tid = threadIdx.x;
    int slot = tid >> 6, lane = tid & 63;
    float bl = ldf(b, b_off + lane, flags[0]);
    for (int n0 = blockIdx.x * 4; n0 < N_NODES; n0 += NBGS * 4) {
        int n = n0 + slot;
        if (n >= N_NODES) continue;
        int end = row_end[n];
        int beg = end - deg[n];
        float acc = swd[(long)n * 64 + lane];
        int p = beg;
        for (; p + 4 <= end; p += 4) {
            int i0 = csr_src[p], i1 = csr_src[p + 1], i2 = csr_src[p + 2], i3 = csr_src[p + 3];
            float v0 = swd[(long)i0 * 64 + lane];
            float v1 = swd[(long)i1 * 64 + lane];
            float v2 = swd[(long)i2 * 64 + lane];
            float v3 = swd[(long)i3 * 64 + lane];
            acc += (v0 + v1) + (v2 + v3);
        }
        for (; p < end; p++) acc += swd[(long)csr_src[p] * 64 + lane];
        s[(long)n * 64 + lane] = tanhf(dinv[n] * acc + bl);
    }
}

// ---------------- pool: run-length segmented sum over sorted batch ----------------
__global__ __launch_bounds__(256) void k_pool(const float* __restrict__ xw,
                                              const int* __restrict__ batch,
                                              const int* __restrict__ flags,
                                              float* __restrict__ xp) {
    int tid = threadIdx.x;
    int slot = tid >> 6, lane = tid & 63;
    int nbeg = (blockIdx.x * 4 + slot) * 16;
    if (nbeg >= N_NODES) return;
    int nend = nbeg + 16;
    if (nend > N_NODES) nend = N_NODES;
    int i64 = flags[1];
    int g = geti(batch, nbeg, i64);
    float acc = 0.f;
    for (int n = nbeg; n < nend; n++) {
        int gn = geti(batch, n, i64);
        if (gn != g) { atomicAdd(&xp[(long)g * 64 + lane], acc); acc = 0.f; g = gn; }
        acc += xw[(long)n * 64 + lane];
    }
    atomicAdd(&xp[(long)g * 64 + lane], acc);
}

// ---------------- final: post + readout + log_softmax ----------------
__global__ __launch_bounds__(64) void k_final(const float* __restrict__ xp,
                                              const void* __restrict__ post_w,
                                              const void* __restrict__ post_b,
                                              const void* __restrict__ ro_w,
                                              const void* __restrict__ ro_b,
                                              const int* __restrict__ flags,
                                              void* __restrict__ out) {
    __shared__ float h2[64];
    __shared__ float lg[16];
    int isf32 = flags[0];
    int g = blockIdx.x;
    int f = threadIdx.x;
    float xr = xp[(long)g * 64 + f];
    float acc = ldf(post_b, f, isf32);
    #pragma unroll
    for (int j = 0; j < 64; j++) acc += __shfl(xr, j) * ldf(post_w, j * 64 + f, isf32);
    float v = fmaxf(acc, 0.f);
    h2[f] = v;
    long oxp = (long)g * 64 + f;
    if (isf32) ((float*)out)[oxp] = v; else ((bf16*)out)[oxp] = f2b(v);
    __syncthreads();
    if (f < 16) {
        float a = ldf(ro_b, f, isf32);
        for (int j = 0; j < 64; j++) a += h2[j] * ldf(ro_w, j * 16 + f, isf32);
        lg[f] = a;
    }
    __syncthreads();
    if (f < 16) {
        float m = -1e30f;
        for (int j = 0; j < 16; j++) m = fmaxf(m, lg[j]);
        float sum = 0.f;
        for (int j = 0; j < 16; j++) sum += expf(lg[j] - m);
        long oy = (long)N_GRAPHS * 64 + (long)g * 16 + f;
        float yv = lg[f] - m - logf(sum);
        if (isf32) ((float*)out)[oy] = yv; else ((bf16*)out)[oy] = f2b(yv);
    }
}

extern "C" void kernel_launch(void* const* d_in, const int* in_sizes, int n_in,
                              void* d_out, int out_size, void* d_ws, size_t ws_size,
                              hipStream_t stream) {
    const void* x_in  = d_in[0];
    const void* s_in  = d_in[1];
    const int*  ei    = (const int*)d_in[2];
    const int*  batch = (const int*)d_in[3];
    const void* pre_w = d_in[4];
    const void* pre_b = d_in[5];
    const void* emb_w = d_in[6];
    const void* emb_b = d_in[7];
    const void* gin_w1 = d_in[8];
    const void* gin_b1 = d_in[9];
    const void* gin_w2 = d_in[10];
    const void* gin_b2 = d_in[11];
    const void* gcn_w  = d_in[12];
    const void* gcn_b  = d_in[13];
    const void* whp_w  = d_in[14];
    const void* whp_b  = d_in[15];
    const void* post_w = d_in[16];
    const void* post_b = d_in[17];
    const void* ro_w   = d_in[18];
    const void* ro_b   = d_in[19];

    // ws (32-bit words): flags(64) | deg(N) | row_end(N) | bsum(512) | csr_src(E)
    //                  | dinv(N) | x0(64N) | x1(64N) | sA(64N) | zb(64N) | xp(G*64)
    int* flags   = (int*)d_ws;
    int* deg     = flags + 64;
    int* row_pos = deg + N_NODES;
    int* bsum    = row_pos + N_NODES;
    int* csr_src = bsum + 512;
    float* dinv  = (float*)(csr_src + N_EDGES);
    float* x0    = dinv + N_NODES;
    float* x1    = x0 + (long)N_NODES * 64;
    float* sA    = x1 + (long)N_NODES * 64;
    float* zb    = sA + (long)N_NODES * 64;
    float* xp    = zb + (long)N_NODES * 64;

    const int nbN = (N_NODES + 255) / 256;
    const int nbE = (N_EDGES + 255) / 256;

    k_detect<<<1, 64, 0, stream>>>(x_in, ei, flags);

    // CSR + dinv
    hipMemsetAsync(deg, 0, N_NODES * sizeof(int), stream);
    k_deg<<<nbE, 256, 0, stream>>>(ei, flags, deg);
    k_dinv<<<nbN, 256, 0, stream>>>(deg, dinv);
    k_scan_block<<<nbN, 256, 0, stream>>>(deg, row_pos, bsum);
    k_scan_bsum<<<1, 512, 0, stream>>>(bsum, nbN);
    k_scan_add<<<nbN, 256, 0, stream>>>(row_pos, bsum);
    k_build_csr<<<nbE, 256, 0, stream>>>(ei, flags, row_pos, csr_src);  // row_pos -> ends

    // pre / embedding
    k_pre<<<NBGS, 256, 0, stream>>>(x_in, pre_w, pre_b, flags, x0);
    k_emb<<<NBGS, 256, 0, stream>>>(s_in, emb_w, emb_b, flags, sA);

    const long W1 = 128 * 64, W2 = 64 * 64, WG = 64 * 64, B = 64;

    // layer 0: x0 -> x1
    k_linear128<<<NBGS, 256, 0, stream>>>(x0, sA, gin_w1, gin_b1, flags, 0L, 0L, 0, zb);
    k_gin_gather<<<NBGS, 256, 0, stream>>>(zb, row_pos, deg, csr_src,
                                           gin_w2, gin_b1, gin_b2, flags, 0L, 0L, x1);
    k_linear_gcn<<<NBGS, 256, 0, stream>>>(sA, dinv, gcn_w, flags, 0L, zb);
    k_gcn_gather<<<NBGS, 256, 0, stream>>>(zb, row_pos, deg, csr_src, dinv, gcn_b, flags, 0L, sA);

    // layer 1: x1 -> x0
    k_linear128<<<NBGS, 256, 0, stream>>>(x1, sA, gin_w1, gin_b1, flags, W1, B, 0, zb);
    k_gin_gather<<<NBGS, 256, 0, stream>>>(zb, row_pos, deg, csr_src,
                                           gin_w2, gin_b1, gin_b2, flags, W2, B, x0);
    k_linear_gcn<<<NBGS, 256, 0, stream>>>(sA, dinv, gcn_w, flags, WG, zb);
    k_gcn_gather<<<NBGS, 256, 0, stream>>>(zb, row_pos, deg, csr_src, dinv, gcn_b, flags, B, sA);

    // head
    k_linear128<<<NBGS, 256, 0, stream>>>(x0, sA, whp_w, whp_b, flags, 0L, 0L, 1, zb);
    hipMemsetAsync(xp, 0, (size_t)N_GRAPHS * 64 * sizeof(float), stream);
    k_pool<<<(N_NODES + 63) / 64, 256, 0, stream>>>(zb, batch, flags, xp);

    k_final<<<N_GRAPHS, 64, 0, stream>>>(xp, post_w, post_b, ro_w, ro_b, flags, d_out);
}

// Round 5
// 787.442 us; speedup vs baseline: 12.4767x; 2.2321x over previous
//
#include <hip/hip_runtime.h>
#include <hip/hip_bf16.h>

#define N_NODES 100000
#define N_EDGES 1600000
#define N_GRAPHS 512
#define NTILES (N_NODES / 16)   // 6250, exact

typedef __hip_bfloat16 bf16;
typedef unsigned int uint;
typedef unsigned short ushort;
typedef __attribute__((ext_vector_type(8))) short short8;
typedef __attribute__((ext_vector_type(4))) float float4v;

__device__ __forceinline__ float b2f(bf16 v) { return __bfloat162float(v); }
__device__ __forceinline__ bf16 f2b(float v) { return __float2bfloat16(v); }

__device__ __forceinline__ float ldf(const void* p, long i, int isf32) {
    return isf32 ? ((const float*)p)[i] : b2f(((const bf16*)p)[i]);
}
__device__ __forceinline__ int geti(const int* p, long i, int is64) {
    return is64 ? p[2 * i] : p[i];
}
__device__ __forceinline__ float bflo(uint u) { return __uint_as_float(u << 16); }
__device__ __forceinline__ float bfhi(uint u) { return __uint_as_float(u & 0xffff0000u); }
__device__ __forceinline__ uint packbf(float x, float y) {
    bf16 a = f2b(x), b = f2b(y);
    ushort ua = *(ushort*)&a, ub = *(ushort*)&b;
    return (uint)ua | ((uint)ub << 16);
}

// ---------------- dtype detection ----------------
__global__ void k_detect(const void* __restrict__ x, const int* __restrict__ ei,
                         int* __restrict__ flags) {
    if (threadIdx.x != 0 || blockIdx.x != 0) return;
    const ushort* xu = (const ushort*)x;
    int plaus = 0;
    for (int i = 0; i < 256; i++) {
        ushort u = xu[2 * i];
        int e = (u >> 7) & 0xFF;
        if (u == 0 || (e >= 116 && e <= 132)) plaus++;
    }
    flags[0] = (plaus < 128) ? 1 : 0;          // 1 => fp32 inputs
    int nz = 0;
    for (int i = 0; i < 128; i++) if (ei[2 * i + 1] != 0) nz++;
    flags[1] = (nz < 8) ? 1 : 0;               // 1 => int64 indices
}

// ---------------- degree / dinv ----------------
__global__ void k_deg(const int* __restrict__ ei, const int* __restrict__ flags,
                      int* __restrict__ deg) {
    int e = blockIdx.x * blockDim.x + threadIdx.x;
    if (e < N_EDGES) atomicAdd(&deg[geti(ei, (long)N_EDGES + e, flags[1])], 1);
}

__global__ void k_dinv(const int* __restrict__ deg, float* __restrict__ dinv) {
    int n = blockIdx.x * blockDim.x + threadIdx.x;
    if (n < N_NODES) dinv[n] = rsqrtf((float)deg[n] + 1.0f);
}

// ---------------- CSR build ----------------
__global__ __launch_bounds__(256) void k_scan_block(const int* __restrict__ deg,
                                                    int* __restrict__ excl,
                                                    int* __restrict__ bsum) {
    __shared__ int tmp[256];
    int tid = threadIdx.x;
    int i = blockIdx.x * 256 + tid;
    int v = (i < N_NODES) ? deg[i] : 0;
    tmp[tid] = v;
    __syncthreads();
    for (int off = 1; off < 256; off <<= 1) {
        int t = (tid >= off) ? tmp[tid - off] : 0;
        __syncthreads();
        tmp[tid] += t;
        __syncthreads();
    }
    if (i < N_NODES) excl[i] = tmp[tid] - v;
    if (tid == 255) bsum[blockIdx.x] = tmp[255];
}

__global__ __launch_bounds__(512) void k_scan_bsum(int* __restrict__ bsum, int nb) {
    __shared__ int tmp[512];
    int tid = threadIdx.x;
    int v = (tid < nb) ? bsum[tid] : 0;
    tmp[tid] = v;
    __syncthreads();
    for (int off = 1; off < 512; off <<= 1) {
        int t = (tid >= off) ? tmp[tid - off] : 0;
        __syncthreads();
        tmp[tid] += t;
        __syncthreads();
    }
    if (tid < nb) bsum[tid] = tmp[tid] - v;
}

__global__ void k_scan_add(int* __restrict__ excl, const int* __restrict__ bsum) {
    int i = blockIdx.x * 256 + threadIdx.x;
    if (i < N_NODES) excl[i] += bsum[blockIdx.x];
}

__global__ void k_build_csr(const int* __restrict__ ei, const int* __restrict__ flags,
                            int* __restrict__ row_pos, int* __restrict__ csr_src) {
    int e = blockIdx.x * blockDim.x + threadIdx.x;
    if (e >= N_EDGES) return;
    int i64 = flags[1];
    int r = geti(ei, e, i64);
    int c = geti(ei, (long)N_EDGES + e, i64);
    int pos = atomicAdd(&row_pos[c], 1);
    csr_src[pos] = r;
}

// ---------------- MFMA node-linear ----------------
// out[n][f] = act( scale? dinv[n]* : 1 * (sum_k A[n][k]*W[k*64+f]) + bias[f] )
// K: padded K (mult of 32); KA: actual K.
// AMODE 0: A0 = bf16 [N,K] in ws.  1: A0 = global input [N,KA], dtype per flags.
//       2: A = concat(A0,A1), both bf16 [N,64], K must be 128.
template <int K, int KA, int AMODE, int BIAS, int ACT, int SCALE, int OUTF32>
__global__ __launch_bounds__(256) void k_mm(const void* __restrict__ A0,
                                            const void* __restrict__ A1,
                                            const void* __restrict__ W,
                                            const void* __restrict__ Bv,
                                            const float* __restrict__ dinv,
                                            const int* __restrict__ flags,
                                            long w_off, long b_off,
                                            void* __restrict__ outp) {
    __shared__ short wT[64 * (K + 8)];   // +8 shorts pad: de-conflict frag reads
    __shared__ float bl[64];
    const int isf32 = flags[0];
    const int tid = threadIdx.x;
    for (int i = tid; i < 64 * K; i += 256) {
        int f = i / K, k = i - f * K;
        float v = (k < KA) ? ldf(W, w_off + (long)k * 64 + f, isf32) : 0.f;
        bf16 h = f2b(v);
        wT[f * (K + 8) + k] = *(short*)&h;
    }
    if (BIAS && tid < 64) bl[tid] = ldf(Bv, b_off + tid, isf32);
    __syncthreads();

    const int lane = tid & 63, wv = tid >> 6;
    const int m = lane & 15, quad = lane >> 4;

    short8 bfr[4][K / 32];
    #pragma unroll
    for (int cb = 0; cb < 4; cb++)
        #pragma unroll
        for (int ks = 0; ks < K / 32; ks++)
            bfr[cb][ks] = *(const short8*)&wT[(cb * 16 + m) * (K + 8) + ks * 32 + quad * 8];

    for (int t = blockIdx.x * 4 + wv; t < NTILES; t += gridDim.x * 4) {
        const int n0 = t * 16;
        short8 af[K / 32];
        if (AMODE == 0) {
            const bf16* Ab = (const bf16*)A0;
            #pragma unroll
            for (int ks = 0; ks < K / 32; ks++)
                af[ks] = *(const short8*)&Ab[(long)(n0 + m) * K + ks * 32 + quad * 8];
        } else if (AMODE == 2) {
            const bf16* Xb = (const bf16*)A0;
            const bf16* Sb = (const bf16*)A1;
            #pragma unroll
            for (int ks = 0; ks < 4; ks++) {
                const bf16* base = (ks < 2) ? &Xb[(long)(n0 + m) * 64 + ks * 32]
                                            : &Sb[(long)(n0 + m) * 64 + (ks - 2) * 32];
                af[ks] = *(const short8*)&base[quad * 8];
            }
        } else {
            #pragma unroll
            for (int ks = 0; ks < K / 32; ks++) {
                short8 a;
                #pragma unroll
                for (int j = 0; j < 8; j++) {
                    int k = ks * 32 + quad * 8 + j;
                    float v = (k < KA) ? ldf(A0, (long)(n0 + m) * KA + k, isf32) : 0.f;
                    bf16 h = f2b(v);
                    a[j] = *(short*)&h;
                }
                af[ks] = a;
            }
        }
        float4v c[4];
        #pragma unroll
        for (int cb = 0; cb < 4; cb++) { c[cb][0] = 0.f; c[cb][1] = 0.f; c[cb][2] = 0.f; c[cb][3] = 0.f; }
        #pragma unroll
        for (int ks = 0; ks < K / 32; ks++)
            #pragma unroll
            for (int cb = 0; cb < 4; cb++)
                c[cb] = __builtin_amdgcn_mfma_f32_16x16x32_bf16(af[ks], bfr[cb][ks], c[cb], 0, 0, 0);
        // epilogue: C/D layout col=lane&15 (feat block), row=quad*4+r (node)
        #pragma unroll
        for (int cb = 0; cb < 4; cb++) {
            int feat = cb * 16 + m;
            float bb = BIAS ? bl[feat] : 0.f;
            #pragma unroll
            for (int r = 0; r < 4; r++) {
                int n = n0 + quad * 4 + r;
                float v = c[cb][r] + bb;
                if (SCALE) v *= dinv[n];
                if (ACT) v = fmaxf(v, 0.f);
                if (OUTF32) ((float*)outp)[(long)n * 64 + feat] = v;
                else { ((bf16*)outp)[(long)n * 64 + feat] = f2b(v); }
            }
        }
    }
}

// ---------------- GIN gather: hid[n] = relu(z[n] + sum_nb z[src] + b1) ----------------
// 2 nodes per wave; lane covers 2 features via uint loads.
__global__ __launch_bounds__(256) void k_gin_gather(const bf16* __restrict__ z,
                                                    const int* __restrict__ row_end,
                                                    const int* __restrict__ deg,
                                                    const int* __restrict__ csr_src,
                                                    const void* __restrict__ b1,
                                                    const int* __restrict__ flags,
                                                    long b_off,
                                                    bf16* __restrict__ hid) {
    int tid = threadIdx.x;
    int wv = tid >> 6, lane = tid & 63;
    int half = lane >> 5, fl = lane & 31;
    int isf32 = flags[0];
    float bb0 = ldf(b1, b_off + 2 * fl, isf32);
    float bb1 = ldf(b1, b_off + 2 * fl + 1, isf32);
    const uint* zp = (const uint*)z;
    uint* hp = (uint*)hid;
    for (int pr = blockIdx.x * 4 + wv; pr < N_NODES / 2; pr += gridDim.x * 4) {
        int n = pr * 2 + half;
        int end = row_end[n];
        int beg = end - deg[n];
        uint u = zp[(long)n * 32 + fl];
        float a0 = bflo(u), a1 = bfhi(u);
        int p = beg;
        for (; p + 8 <= end; p += 8) {
            int i0 = csr_src[p], i1 = csr_src[p + 1], i2 = csr_src[p + 2], i3 = csr_src[p + 3];
            int i4 = csr_src[p + 4], i5 = csr_src[p + 5], i6 = csr_src[p + 6], i7 = csr_src[p + 7];
            uint u0 = zp[(long)i0 * 32 + fl], u1 = zp[(long)i1 * 32 + fl];
            uint u2 = zp[(long)i2 * 32 + fl], u3 = zp[(long)i3 * 32 + fl];
            uint u4 = zp[(long)i4 * 32 + fl], u5 = zp[(long)i5 * 32 + fl];
            uint u6 = zp[(long)i6 * 32 + fl], u7 = zp[(long)i7 * 32 + fl];
            a0 += ((bflo(u0) + bflo(u1)) + (bflo(u2) + bflo(u3)))
                + ((bflo(u4) + bflo(u5)) + (bflo(u6) + bflo(u7)));
            a1 += ((bfhi(u0) + bfhi(u1)) + (bfhi(u2) + bfhi(u3)))
                + ((bfhi(u4) + bfhi(u5)) + (bfhi(u6) + bfhi(u7)));
        }
        for (; p < end; p++) {
            uint uu = zp[(long)csr_src[p] * 32 + fl];
            a0 += bflo(uu); a1 += bfhi(uu);
        }
        hp[(long)n * 32 + fl] = packbf(fmaxf(a0 + bb0, 0.f), fmaxf(a1 + bb1, 0.f));
    }
}

// ---------------- GCN gather: s[n] = tanh(dinv[n]*(swd[n]+sum_nb swd[src]) + b) ----------------
__global__ __launch_bounds__(256) void k_gcn_gather(const bf16* __restrict__ swd,
                                                    const int* __restrict__ row_end,
                                                    const int* __restrict__ deg,
                                                    const int* __restrict__ csr_src,
                                                    const float* __restrict__ dinv,
                                                    const void* __restrict__ b,
                                                    const int* __restrict__ flags,
                                                    long b_off,
                                                    bf16* __restrict__ s) {
    int tid = threadIdx.x;
    int wv = tid >> 6, lane = tid & 63;
    int half = lane >> 5, fl = lane & 31;
    int isf32 = flags[0];
    float bb0 = ldf(b, b_off + 2 * fl, isf32);
    float bb1 = ldf(b, b_off + 2 * fl + 1, isf32);
    const uint* zp = (const uint*)swd;
    uint* sp = (uint*)s;
    for (int pr = blockIdx.x * 4 + wv; pr < N_NODES / 2; pr += gridDim.x * 4) {
        int n = pr * 2 + half;
        int end = row_end[n];
        int beg = end - deg[n];
        float dn = dinv[n];
        uint u = zp[(long)n * 32 + fl];
        float a0 = bflo(u), a1 = bfhi(u);
        int p = beg;
        for (; p + 8 <= end; p += 8) {
            int i0 = csr_src[p], i1 = csr_src[p + 1], i2 = csr_src[p + 2], i3 = csr_src[p + 3];
            int i4 = csr_src[p + 4], i5 = csr_src[p + 5], i6 = csr_src[p + 6], i7 = csr_src[p + 7];
            uint u0 = zp[(long)i0 * 32 + fl], u1 = zp[(long)i1 * 32 + fl];
            uint u2 = zp[(long)i2 * 32 + fl], u3 = zp[(long)i3 * 32 + fl];
            uint u4 = zp[(long)i4 * 32 + fl], u5 = zp[(long)i5 * 32 + fl];
            uint u6 = zp[(long)i6 * 32 + fl], u7 = zp[(long)i7 * 32 + fl];
            a0 += ((bflo(u0) + bflo(u1)) + (bflo(u2) + bflo(u3)))
                + ((bflo(u4) + bflo(u5)) + (bflo(u6) + bflo(u7)));
            a1 += ((bfhi(u0) + bfhi(u1)) + (bfhi(u2) + bfhi(u3)))
                + ((bfhi(u4) + bfhi(u5)) + (bfhi(u6) + bfhi(u7)));
        }
        for (; p < end; p++) {
            uint uu = zp[(long)csr_src[p] * 32 + fl];
            a0 += bflo(uu); a1 += bfhi(uu);
        }
        sp[(long)n * 32 + fl] = packbf(tanhf(dn * a0 + bb0), tanhf(dn * a1 + bb1));
    }
}

// ---------------- pool: run-length segmented sum over sorted batch ----------------
__global__ __launch_bounds__(256) void k_pool(const float* __restrict__ xw,
                                              const int* __restrict__ batch,
                                              const int* __restrict__ flags,
                                              float* __restrict__ xp) {
    int tid = threadIdx.x;
    int slot = tid >> 6, lane = tid & 63;
    int nbeg = (blockIdx.x * 4 + slot) * 16;
    if (nbeg >= N_NODES) return;
    int nend = nbeg + 16;
    if (nend > N_NODES) nend = N_NODES;
    int i64 = flags[1];
    int g = geti(batch, nbeg, i64);
    float acc = 0.f;
    for (int n = nbeg; n < nend; n++) {
        int gn = geti(batch, n, i64);
        if (gn != g) { atomicAdd(&xp[(long)g * 64 + lane], acc); acc = 0.f; g = gn; }
        acc += xw[(long)n * 64 + lane];
    }
    atomicAdd(&xp[(long)g * 64 + lane], acc);
}

// ---------------- final: post + readout + log_softmax ----------------
__global__ __launch_bounds__(64) void k_final(const float* __restrict__ xp,
                                              const void* __restrict__ post_w,
                                              const void* __restrict__ post_b,
                                              const void* __restrict__ ro_w,
                                              const void* __restrict__ ro_b,
                                              const int* __restrict__ flags,
                                              void* __restrict__ out) {
    __shared__ float h2[64];
    __shared__ float lg[16];
    int isf32 = flags[0];
    int g = blockIdx.x;
    int f = threadIdx.x;
    float xr = xp[(long)g * 64 + f];
    float acc = ldf(post_b, f, isf32);
    #pragma unroll
    for (int j = 0; j < 64; j++) acc += __shfl(xr, j) * ldf(post_w, j * 64 + f, isf32);
    float v = fmaxf(acc, 0.f);
    h2[f] = v;
    long oxp = (long)g * 64 + f;
    if (isf32) ((float*)out)[oxp] = v; else ((bf16*)out)[oxp] = f2b(v);
    __syncthreads();
    if (f < 16) {
        float a = ldf(ro_b, f, isf32);
        for (int j = 0; j < 64; j++) a += h2[j] * ldf(ro_w, j * 16 + f, isf32);
        lg[f] = a;
    }
    __syncthreads();
    if (f < 16) {
        float m = -1e30f;
        for (int j = 0; j < 16; j++) m = fmaxf(m, lg[j]);
        float sum = 0.f;
        for (int j = 0; j < 16; j++) sum += expf(lg[j] - m);
        long oy = (long)N_GRAPHS * 64 + (long)g * 16 + f;
        float yv = lg[f] - m - logf(sum);
        if (isf32) ((float*)out)[oy] = yv; else ((bf16*)out)[oy] = f2b(yv);
    }
}

extern "C" void kernel_launch(void* const* d_in, const int* in_sizes, int n_in,
                              void* d_out, int out_size, void* d_ws, size_t ws_size,
                              hipStream_t stream) {
    const void* x_in  = d_in[0];
    const void* s_in  = d_in[1];
    const int*  ei    = (const int*)d_in[2];
    const int*  batch = (const int*)d_in[3];
    const void* pre_w = d_in[4];
    const void* pre_b = d_in[5];
    const void* emb_w = d_in[6];
    const void* emb_b = d_in[7];
    const void* gin_w1 = d_in[8];
    const void* gin_b1 = d_in[9];
    const void* gin_w2 = d_in[10];
    const void* gin_b2 = d_in[11];
    const void* gcn_w  = d_in[12];
    const void* gcn_b  = d_in[13];
    const void* whp_w  = d_in[14];
    const void* whp_b  = d_in[15];
    const void* post_w = d_in[16];
    const void* post_b = d_in[17];
    const void* ro_w   = d_in[18];
    const void* ro_b   = d_in[19];

    // ws: flags(64i) | deg(N) | row_end(N) | bsum(512) | csr_src(E) | dinv(N f32)
    //   | x0,x1,sA,zA,hB (bf16 N*64 each) | wout(f32 N*64) | xp(f32 G*64)
    int* flags   = (int*)d_ws;
    int* deg     = flags + 64;
    int* row_pos = deg + N_NODES;
    int* bsum    = row_pos + N_NODES;
    int* csr_src = bsum + 512;
    float* dinv  = (float*)(csr_src + N_EDGES);
    bf16* x0     = (bf16*)(dinv + N_NODES);
    bf16* x1     = x0 + (long)N_NODES * 64;
    bf16* sA     = x1 + (long)N_NODES * 64;
    bf16* zA     = sA + (long)N_NODES * 64;
    bf16* hB     = zA + (long)N_NODES * 64;
    float* wout  = (float*)(hB + (long)N_NODES * 64);
    float* xp    = wout + (long)N_NODES * 64;

    const int nbN = (N_NODES + 255) / 256;
    const int nbE = (N_EDGES + 255) / 256;
    const int MMB = 512;    // k_mm grid
    const int GGB = 1024;   // gather grid

    k_detect<<<1, 64, 0, stream>>>(x_in, ei, flags);

    // CSR + dinv
    hipMemsetAsync(deg, 0, N_NODES * sizeof(int), stream);
    k_deg<<<nbE, 256, 0, stream>>>(ei, flags, deg);
    k_dinv<<<nbN, 256, 0, stream>>>(deg, dinv);
    k_scan_block<<<nbN, 256, 0, stream>>>(deg, row_pos, bsum);
    k_scan_bsum<<<1, 512, 0, stream>>>(bsum, nbN);
    k_scan_add<<<nbN, 256, 0, stream>>>(row_pos, bsum);
    k_build_csr<<<nbE, 256, 0, stream>>>(ei, flags, row_pos, csr_src);  // row_pos -> ends

    const long W1 = 128 * 64, W2 = 64 * 64, WG = 64 * 64, B = 64;

    // pre / embedding -> bf16 activations
    k_mm<128, 128, 1, 1, 0, 0, 0><<<MMB, 256, 0, stream>>>(x_in, nullptr, pre_w, pre_b, dinv, flags, 0L, 0L, x0);
    k_mm<32, 16, 1, 1, 0, 0, 0><<<MMB, 256, 0, stream>>>(s_in, nullptr, emb_w, emb_b, dinv, flags, 0L, 0L, sA);

    // ---- layer 0: x0 -> x1 ----
    k_mm<128, 128, 2, 0, 0, 0, 0><<<MMB, 256, 0, stream>>>(x0, sA, gin_w1, nullptr, dinv, flags, 0L, 0L, zA);
    k_gin_gather<<<GGB, 256, 0, stream>>>(zA, row_pos, deg, csr_src, gin_b1, flags, 0L, hB);
    k_mm<64, 64, 0, 1, 1, 0, 0><<<MMB, 256, 0, stream>>>(hB, nullptr, gin_w2, gin_b2, dinv, flags, 0L, 0L, x1);
    k_mm<64, 64, 0, 0, 0, 1, 0><<<MMB, 256, 0, stream>>>(sA, nullptr, gcn_w, nullptr, dinv, flags, 0L, 0L, zA);
    k_gcn_gather<<<GGB, 256, 0, stream>>>(zA, row_pos, deg, csr_src, dinv, gcn_b, flags, 0L, sA);

    // ---- layer 1: x1 -> x0 ----
    k_mm<128, 128, 2, 0, 0, 0, 0><<<MMB, 256, 0, stream>>>(x1, sA, gin_w1, nullptr, dinv, flags, W1, 0L, zA);
    k_gin_gather<<<GGB, 256, 0, stream>>>(zA, row_pos, deg, csr_src, gin_b1, flags, B, hB);
    k_mm<64, 64, 0, 1, 1, 0, 0><<<MMB, 256, 0, stream>>>(hB, nullptr, gin_w2, gin_b2, dinv, flags, W2, B, x0);
    k_mm<64, 64, 0, 0, 0, 1, 0><<<MMB, 256, 0, stream>>>(sA, nullptr, gcn_w, nullptr, dinv, flags, WG, 0L, zA);
    k_gcn_gather<<<GGB, 256, 0, stream>>>(zA, row_pos, deg, csr_src, dinv, gcn_b, flags, B, sA);

    // ---- head ----
    k_mm<128, 128, 2, 1, 0, 0, 1><<<MMB, 256, 0, stream>>>(x0, sA, whp_w, whp_b, dinv, flags, 0L, 0L, wout);
    hipMemsetAsync(xp, 0, (size_t)N_GRAPHS * 64 * sizeof(float), stream);
    k_pool<<<(N_NODES + 63) / 64, 256, 0, stream>>>(wout, batch, flags, xp);

    k_final<<<N_GRAPHS, 64, 0, stream>>>(xp, post_w, post_b, ro_w, ro_b, flags, d_out);
}